// Round 6
// baseline (2463.041 us; speedup 1.0000x reference)
//
#include <hip/hip_runtime.h>
#include <cstddef>
#include <cstdint>

#define N_IN  1024
#define N_HID 128
#define N_OUT 3

// ---------------- degree (int atomics) ----------------
__global__ void k_deg(const int* __restrict__ dst, int E, int* __restrict__ deg) {
  int i = blockIdx.x * blockDim.x + threadIdx.x;
  int stride = gridDim.x * blockDim.x;
  for (int e = i; e < E; e += stride) atomicAdd(deg + dst[e], 1);
}

// dis[i] = rsqrt(deg_in + 1 self-loop); deg >= 1 always, so no zero-guard needed
__global__ void k_dis(const int* __restrict__ deg, float* __restrict__ dis, int N) {
  int i = blockIdx.x * blockDim.x + threadIdx.x;
  if (i < N) dis[i] = rsqrtf((float)deg[i] + 1.0f);
}

// ---------------- GEMM1: Y[M,128] = X[M,1024] @ W[1024,128], fp32 ----------------
// 128x128 block tile, BK=16, 256 threads (4 waves in 2x2), 8x8 micro-tile.
// Wave-level 2x2 arrangement; lane grid 8x8 => A/B LDS reads are 8-address
// broadcasts (2-way bank alias = free, m136). As padded [16][132] so the
// transposed staging writes are 2-way (free) instead of 4-way.
#define BM 128
#define BK 16
__global__ __launch_bounds__(256) void k_gemm1(const float* __restrict__ X,
                                               const float* __restrict__ W,
                                               float* __restrict__ Y, int M) {
  __shared__ float As[BK][132];     // A^T tile: As[k][m], padded 128->132
  __shared__ float Bs[BK][N_HID];   // Bs[k][n]
  const int t = threadIdx.x;
  const int brow = blockIdx.x * BM;
  const int wave = t >> 6;
  const int lane = t & 63;
  const int wr = (wave >> 1) * 64;   // wave row offset: 0 or 64
  const int wc = (wave & 1) * 64;    // wave col offset: 0 or 64
  const int ar = wr + (lane >> 3) * 8;  // this thread's 8 rows
  const int bc = wc + (lane & 7) * 8;   // this thread's 8 cols

  float acc[8][8];
#pragma unroll
  for (int i = 0; i < 8; ++i)
#pragma unroll
    for (int j = 0; j < 8; ++j) acc[i][j] = 0.f;

  for (int k0 = 0; k0 < N_IN; k0 += BK) {
    // stage A: 512 float4 loads = 128 rows x 16 k; store transposed
#pragma unroll
    for (int u = 0; u < 2; ++u) {
      int f = t + u * 256;            // 0..511
      int row = f >> 2;               // 0..127
      int kq = (f & 3) * 4;           // 0,4,8,12
      int grow = brow + row;
      if (grow > M - 1) grow = M - 1; // clamp (stores are guarded)
      float4 va = *(const float4*)(X + (size_t)grow * N_IN + k0 + kq);
      As[kq + 0][row] = va.x;
      As[kq + 1][row] = va.y;
      As[kq + 2][row] = va.z;
      As[kq + 3][row] = va.w;
    }
    // stage B: 16 rows x 128 cols
#pragma unroll
    for (int u = 0; u < 2; ++u) {
      int f = t + u * 256;            // 0..511
      int kr = f >> 5;                // 0..15
      int nc = (f & 31) * 4;          // 0..124
      *(float4*)&Bs[kr][nc] = *(const float4*)(W + (size_t)(k0 + kr) * N_HID + nc);
    }
    __syncthreads();
#pragma unroll
    for (int k = 0; k < BK; ++k) {
      float4 a0 = *(const float4*)&As[k][ar];
      float4 a1 = *(const float4*)&As[k][ar + 4];
      float4 b0 = *(const float4*)&Bs[k][bc];
      float4 b1 = *(const float4*)&Bs[k][bc + 4];
      float av[8] = {a0.x, a0.y, a0.z, a0.w, a1.x, a1.y, a1.z, a1.w};
      float bv[8] = {b0.x, b0.y, b0.z, b0.w, b1.x, b1.y, b1.z, b1.w};
#pragma unroll
      for (int i = 0; i < 8; ++i)
#pragma unroll
        for (int j = 0; j < 8; ++j) acc[i][j] += av[i] * bv[j];
    }
    __syncthreads();
  }
#pragma unroll
  for (int i = 0; i < 8; ++i) {
    int row = brow + ar + i;
    if (row < M) {
      float4 v0 = make_float4(acc[i][0], acc[i][1], acc[i][2], acc[i][3]);
      float4 v1 = make_float4(acc[i][4], acc[i][5], acc[i][6], acc[i][7]);
      *(float4*)(Y + (size_t)row * N_HID + bc) = v0;
      *(float4*)(Y + (size_t)row * N_HID + bc + 4) = v1;
    }
  }
}

// ---------------- scatter1: agg1[dst] += x1[src] * dis[src]*dis[dst] ----------------
// wave per edge, lane handles 2 channels (float2 => coalesced 512B wave read)
__global__ void k_scatter1(const float* __restrict__ x1, const int* __restrict__ src,
                           const int* __restrict__ dst, const float* __restrict__ dis,
                           float* __restrict__ agg1, int E) {
  int gtid = blockIdx.x * blockDim.x + threadIdx.x;
  int wave = gtid >> 6;
  int lane = threadIdx.x & 63;
  int nwaves = (gridDim.x * blockDim.x) >> 6;
  for (int e = wave; e < E; e += nwaves) {
    int s = __ldg(src + e);
    int d = __ldg(dst + e);
    float n = __ldg(dis + s) * __ldg(dis + d);
    float2 v = *(const float2*)(x1 + (size_t)s * N_HID + lane * 2);
    atomicAdd(agg1 + (size_t)d * N_HID + lane * 2 + 0, v.x * n);
    atomicAdd(agg1 + (size_t)d * N_HID + lane * 2 + 1, v.y * n);
  }
}

// -------- fused: h = relu(agg1 + x1*dis^2 + b1); x2 = h @ W2  (thread per row) -----
__global__ __launch_bounds__(256) void k_h_gemm2(const float* __restrict__ x1,
                                                 const float* __restrict__ agg1,
                                                 const float* __restrict__ dis,
                                                 const float* __restrict__ b1,
                                                 const float* __restrict__ W2,
                                                 float* __restrict__ x2, int N) {
  __shared__ float w2s[N_HID * N_OUT];  // 384 floats — STRIDED staging (384 > 256 threads!)
  __shared__ float b1s[N_HID];
  const int t = threadIdx.x;
  for (int i = t; i < N_HID * N_OUT; i += 256) w2s[i] = W2[i];
  for (int i = t; i < N_HID; i += 256) b1s[i] = b1[i];
  __syncthreads();

  int r = blockIdx.x * blockDim.x + t;
  int stride = gridDim.x * blockDim.x;
  for (; r < N; r += stride) {
    float ds2 = dis[r];
    ds2 *= ds2;
    float a0 = 0.f, a1 = 0.f, a2 = 0.f;
    const float* xr = x1 + (size_t)r * N_HID;
    const float* gr = agg1 + (size_t)r * N_HID;
#pragma unroll
    for (int k4 = 0; k4 < N_HID / 4; ++k4) {
      float4 xv = *(const float4*)(xr + k4 * 4);
      float4 gv = *(const float4*)(gr + k4 * 4);
      float hv[4];
      hv[0] = fmaxf(gv.x + xv.x * ds2 + b1s[k4 * 4 + 0], 0.f);
      hv[1] = fmaxf(gv.y + xv.y * ds2 + b1s[k4 * 4 + 1], 0.f);
      hv[2] = fmaxf(gv.z + xv.z * ds2 + b1s[k4 * 4 + 2], 0.f);
      hv[3] = fmaxf(gv.w + xv.w * ds2 + b1s[k4 * 4 + 3], 0.f);
#pragma unroll
      for (int u = 0; u < 4; ++u) {
        int k = k4 * 4 + u;
        a0 += hv[u] * w2s[k * 3 + 0];
        a1 += hv[u] * w2s[k * 3 + 1];
        a2 += hv[u] * w2s[k * 3 + 2];
      }
    }
    x2[(size_t)r * N_OUT + 0] = a0;
    x2[(size_t)r * N_OUT + 1] = a1;
    x2[(size_t)r * N_OUT + 2] = a2;
  }
}

// ---------------- scatter2: out[dst] += x2[src]*norm (3 ch, thread per edge) -------
__global__ void k_scatter2(const float* __restrict__ x2, const int* __restrict__ src,
                           const int* __restrict__ dst, const float* __restrict__ dis,
                           float* __restrict__ out, int E) {
  int i = blockIdx.x * blockDim.x + threadIdx.x;
  int stride = gridDim.x * blockDim.x;
  for (int e = i; e < E; e += stride) {
    int s = src[e];
    int d = dst[e];
    float n = dis[s] * dis[d];
    atomicAdd(out + (size_t)d * N_OUT + 0, x2[(size_t)s * N_OUT + 0] * n);
    atomicAdd(out + (size_t)d * N_OUT + 1, x2[(size_t)s * N_OUT + 1] * n);
    atomicAdd(out + (size_t)d * N_OUT + 2, x2[(size_t)s * N_OUT + 2] * n);
  }
}

// ---------------- final: out += x2*dis^2 + b2 (self-loop + bias) ----------------
__global__ void k_final(const float* __restrict__ x2, const float* __restrict__ dis,
                        const float* __restrict__ b2, float* __restrict__ out, int N) {
  int i = blockIdx.x * blockDim.x + threadIdx.x;
  if (i < N) {
    float ds = dis[i];
    ds *= ds;
    out[(size_t)i * N_OUT + 0] += x2[(size_t)i * N_OUT + 0] * ds + b2[0];
    out[(size_t)i * N_OUT + 1] += x2[(size_t)i * N_OUT + 1] * ds + b2[1];
    out[(size_t)i * N_OUT + 2] += x2[(size_t)i * N_OUT + 2] * ds + b2[2];
  }
}

extern "C" void kernel_launch(void* const* d_in, const int* in_sizes, int n_in,
                              void* d_out, int out_size, void* d_ws, size_t ws_size,
                              hipStream_t stream) {
  const float* X     = (const float*)d_in[0];
  const int*   edges = (const int*)d_in[1];
  // d_in[2] = edges2 (unused), d_in[3] = edge_features (unused)
  const float* W1 = (const float*)d_in[4];
  const float* b1 = (const float*)d_in[5];
  const float* W2 = (const float*)d_in[6];
  const float* b2 = (const float*)d_in[7];
  float* out = (float*)d_out;

  const int N = in_sizes[0] / N_IN;
  const int E = in_sizes[1] / 2;
  const int* src = edges;
  const int* dst = edges + E;

  char* ws = (char*)d_ws;
  size_t off = 0;
  auto alloc = [&](size_t bytes) {
    size_t o = off;
    off += (bytes + 255) & ~(size_t)255;
    return o;
  };
  float* x1   = (float*)(ws + alloc((size_t)N * N_HID * 4));  // 51.2 MB
  float* agg1 = (float*)(ws + alloc((size_t)N * N_HID * 4));  // 51.2 MB
  float* x2   = (float*)(ws + alloc((size_t)N * N_OUT * 4));  // 1.2 MB
  int*   deg  = (int*)  (ws + alloc((size_t)N * 4));
  float* dis  = (float*)(ws + alloc((size_t)N * 4));

  // ws/d_out are poisoned 0xAA before every call — zero what needs zeroing
  (void)hipMemsetAsync(agg1, 0, (size_t)N * N_HID * 4, stream);
  (void)hipMemsetAsync(deg, 0, (size_t)N * 4, stream);
  (void)hipMemsetAsync(out, 0, (size_t)N * N_OUT * 4, stream);

  k_deg<<<2048, 256, 0, stream>>>(dst, E, deg);
  k_dis<<<(N + 255) / 256, 256, 0, stream>>>(deg, dis, N);
  k_gemm1<<<(N + BM - 1) / BM, 256, 0, stream>>>(X, W1, x1, N);
  k_scatter1<<<8192, 256, 0, stream>>>(x1, src, dst, dis, agg1, E);
  k_h_gemm2<<<(N + 255) / 256, 256, 0, stream>>>(x1, agg1, dis, b1, W2, x2, N);
  k_scatter2<<<4096, 256, 0, stream>>>(x2, src, dst, dis, out, E);
  k_final<<<(N + 255) / 256, 256, 0, stream>>>(x2, dis, b2, out, N);
}

// Round 8
// 1225.136 us; speedup vs baseline: 2.0104x; 2.0104x over previous
//
#include <hip/hip_runtime.h>
#include <cstddef>
#include <cstdint>

#define N_IN  1024
#define N_HID 128
#define N_OUT 3

// ---------------- degree (int atomics) ----------------
__global__ void k_deg(const int* __restrict__ dst, int E, int* __restrict__ deg) {
  int i = blockIdx.x * blockDim.x + threadIdx.x;
  int stride = gridDim.x * blockDim.x;
  for (int e = i; e < E; e += stride) atomicAdd(deg + dst[e], 1);
}

// dis[i] = rsqrt(deg_in + 1 self-loop)
__global__ void k_dis(const int* __restrict__ deg, float* __restrict__ dis, int N) {
  int i = blockIdx.x * blockDim.x + threadIdx.x;
  if (i < N) dis[i] = rsqrtf((float)deg[i] + 1.0f);
}

// ---------------- CSR segment assignment: block scan + one atomic per block -------
// Segment ORDER across blocks is arbitrary (atomic bases) — irrelevant for sums.
__global__ __launch_bounds__(256) void k_scan(const int* __restrict__ deg,
                                              int* __restrict__ start,
                                              int* __restrict__ cursor,
                                              int* __restrict__ counter, int N) {
  __shared__ int sh[256];
  __shared__ int base;
  int tid = threadIdx.x;
  int i = blockIdx.x * 256 + tid;
  int v = (i < N) ? deg[i] : 0;
  sh[tid] = v;
  __syncthreads();
  // Hillis-Steele inclusive scan (read -> sync -> write -> sync)
#pragma unroll
  for (int off = 1; off < 256; off <<= 1) {
    int t = (tid >= off) ? sh[tid - off] : 0;
    __syncthreads();
    sh[tid] += t;
    __syncthreads();
  }
  int incl = sh[tid];
  if (tid == 255) base = atomicAdd(counter, incl);
  __syncthreads();
  int excl = base + incl - v;
  if (i < N) { start[i] = excl; cursor[i] = excl; }
}

// ---------------- CSR fill: 1.6M int atomics on cursor ----------------
__global__ void k_fill(const int* __restrict__ src, const int* __restrict__ dst, int E,
                       int* __restrict__ cursor, int* __restrict__ col) {
  int i = blockIdx.x * blockDim.x + threadIdx.x;
  int stride = gridDim.x * blockDim.x;
  for (int e = i; e < E; e += stride) {
    int d = dst[e];
    int pos = atomicAdd(cursor + d, 1);
    col[pos] = src[e];
  }
}

// ---------------- GEMM1: Y[M,128] = X[M,1024] @ W[1024,128], fp32 ----------------
#define BM 128
#define BK 16
__global__ __launch_bounds__(256) void k_gemm1(const float* __restrict__ X,
                                               const float* __restrict__ W,
                                               float* __restrict__ Y, int M) {
  __shared__ float As[BK][132];     // A^T tile, padded
  __shared__ float Bs[BK][N_HID];
  const int t = threadIdx.x;
  const int brow = blockIdx.x * BM;
  const int wave = t >> 6;
  const int lane = t & 63;
  const int wr = (wave >> 1) * 64;
  const int wc = (wave & 1) * 64;
  const int ar = wr + (lane >> 3) * 8;
  const int bc = wc + (lane & 7) * 8;

  float acc[8][8];
#pragma unroll
  for (int i = 0; i < 8; ++i)
#pragma unroll
    for (int j = 0; j < 8; ++j) acc[i][j] = 0.f;

  for (int k0 = 0; k0 < N_IN; k0 += BK) {
#pragma unroll
    for (int u = 0; u < 2; ++u) {
      int f = t + u * 256;
      int row = f >> 2;
      int kq = (f & 3) * 4;
      int grow = brow + row;
      if (grow > M - 1) grow = M - 1;
      float4 va = *(const float4*)(X + (size_t)grow * N_IN + k0 + kq);
      As[kq + 0][row] = va.x;
      As[kq + 1][row] = va.y;
      As[kq + 2][row] = va.z;
      As[kq + 3][row] = va.w;
    }
#pragma unroll
    for (int u = 0; u < 2; ++u) {
      int f = t + u * 256;
      int kr = f >> 5;
      int nc = (f & 31) * 4;
      *(float4*)&Bs[kr][nc] = *(const float4*)(W + (size_t)(k0 + kr) * N_HID + nc);
    }
    __syncthreads();
#pragma unroll
    for (int k = 0; k < BK; ++k) {
      float4 a0 = *(const float4*)&As[k][ar];
      float4 a1 = *(const float4*)&As[k][ar + 4];
      float4 b0 = *(const float4*)&Bs[k][bc];
      float4 b1 = *(const float4*)&Bs[k][bc + 4];
      float av[8] = {a0.x, a0.y, a0.z, a0.w, a1.x, a1.y, a1.z, a1.w};
      float bv[8] = {b0.x, b0.y, b0.z, b0.w, b1.x, b1.y, b1.z, b1.w};
#pragma unroll
      for (int i = 0; i < 8; ++i)
#pragma unroll
        for (int j = 0; j < 8; ++j) acc[i][j] += av[i] * bv[j];
    }
    __syncthreads();
  }
#pragma unroll
  for (int i = 0; i < 8; ++i) {
    int row = brow + ar + i;
    if (row < M) {
      float4 v0 = make_float4(acc[i][0], acc[i][1], acc[i][2], acc[i][3]);
      float4 v1 = make_float4(acc[i][4], acc[i][5], acc[i][6], acc[i][7]);
      *(float4*)(Y + (size_t)row * N_HID + bc) = v0;
      *(float4*)(Y + (size_t)row * N_HID + bc + 4) = v1;
    }
  }
}

// ---- fused gather1 + h + gemm2: wave per node, lane = 2 channels ----
// x2[d] = relu( (sum_in x1[s]*dis[s])*dis[d] + x1[d]*dis[d]^2 + b1 ) @ W2
__global__ __launch_bounds__(256) void k_agg_h_gemm2(const float* __restrict__ x1,
                                                     const int* __restrict__ start,
                                                     const int* __restrict__ deg,
                                                     const int* __restrict__ col,
                                                     const float* __restrict__ dis,
                                                     const float* __restrict__ b1,
                                                     const float* __restrict__ W2,
                                                     float* __restrict__ x2, int N) {
  __shared__ float w2s[N_HID * N_OUT];  // 384
  __shared__ float b1s[N_HID];
  const int t = threadIdx.x;
  for (int i = t; i < N_HID * N_OUT; i += 256) w2s[i] = W2[i];
  for (int i = t; i < N_HID; i += 256) b1s[i] = b1[i];
  __syncthreads();

  const int lane = t & 63;
  const int node = blockIdx.x * 4 + (t >> 6);
  if (node >= N) return;

  const int s0 = start[node];
  const int dg = deg[node];
  const float dd = dis[node];

  float a0 = 0.f, a1 = 0.f;
  for (int j = 0; j < dg; ++j) {
    int s = col[s0 + j];                 // wave-uniform -> broadcast load
    float ds = dis[s];
    float2 v = *(const float2*)(x1 + (size_t)s * N_HID + lane * 2);
    a0 += v.x * ds;
    a1 += v.y * ds;
  }
  float2 vs = *(const float2*)(x1 + (size_t)node * N_HID + lane * 2);
  float sl = dd * dd;
  a0 = a0 * dd + vs.x * sl;
  a1 = a1 * dd + vs.y * sl;
  float h0 = fmaxf(a0 + b1s[lane * 2 + 0], 0.f);
  float h1 = fmaxf(a1 + b1s[lane * 2 + 1], 0.f);

  float c0 = h0 * w2s[(lane * 2) * 3 + 0] + h1 * w2s[(lane * 2 + 1) * 3 + 0];
  float c1 = h0 * w2s[(lane * 2) * 3 + 1] + h1 * w2s[(lane * 2 + 1) * 3 + 1];
  float c2 = h0 * w2s[(lane * 2) * 3 + 2] + h1 * w2s[(lane * 2 + 1) * 3 + 2];
#pragma unroll
  for (int off = 32; off > 0; off >>= 1) {
    c0 += __shfl_down(c0, off, 64);
    c1 += __shfl_down(c1, off, 64);
    c2 += __shfl_down(c2, off, 64);
  }
  if (lane == 0) {
    x2[(size_t)node * N_OUT + 0] = c0;
    x2[(size_t)node * N_OUT + 1] = c1;
    x2[(size_t)node * N_OUT + 2] = c2;
  }
}

// ---- fused gather2 + self-loop + bias: thread per node, full write of out ----
__global__ void k_g2(const float* __restrict__ x2, const int* __restrict__ start,
                     const int* __restrict__ deg, const int* __restrict__ col,
                     const float* __restrict__ dis, const float* __restrict__ b2,
                     float* __restrict__ out, int N) {
  int d = blockIdx.x * blockDim.x + threadIdx.x;
  if (d >= N) return;
  int s0 = start[d];
  int dg = deg[d];
  float dd = dis[d];
  float a0 = 0.f, a1 = 0.f, a2 = 0.f;
  for (int j = 0; j < dg; ++j) {
    int s = col[s0 + j];
    float ds = dis[s];
    a0 += x2[(size_t)s * N_OUT + 0] * ds;
    a1 += x2[(size_t)s * N_OUT + 1] * ds;
    a2 += x2[(size_t)s * N_OUT + 2] * ds;
  }
  float sl = dd * dd;
  out[(size_t)d * N_OUT + 0] = a0 * dd + x2[(size_t)d * N_OUT + 0] * sl + b2[0];
  out[(size_t)d * N_OUT + 1] = a1 * dd + x2[(size_t)d * N_OUT + 1] * sl + b2[1];
  out[(size_t)d * N_OUT + 2] = a2 * dd + x2[(size_t)d * N_OUT + 2] * sl + b2[2];
}

extern "C" void kernel_launch(void* const* d_in, const int* in_sizes, int n_in,
                              void* d_out, int out_size, void* d_ws, size_t ws_size,
                              hipStream_t stream) {
  const float* X     = (const float*)d_in[0];
  const int*   edges = (const int*)d_in[1];
  // d_in[2] = edges2 (unused), d_in[3] = edge_features (unused)
  const float* W1 = (const float*)d_in[4];
  const float* b1 = (const float*)d_in[5];
  const float* W2 = (const float*)d_in[6];
  const float* b2 = (const float*)d_in[7];
  float* out = (float*)d_out;

  const int N = in_sizes[0] / N_IN;
  const int E = in_sizes[1] / 2;
  const int* src = edges;
  const int* dst = edges + E;

  char* ws = (char*)d_ws;
  size_t off = 0;
  auto alloc = [&](size_t bytes) {
    size_t o = off;
    off += (bytes + 255) & ~(size_t)255;
    return o;
  };
  float* x1     = (float*)(ws + alloc((size_t)N * N_HID * 4));  // 51.2 MB
  float* x2     = (float*)(ws + alloc((size_t)N * N_OUT * 4));  // 1.2 MB
  int*   deg    = (int*)  (ws + alloc((size_t)N * 4));
  float* dis    = (float*)(ws + alloc((size_t)N * 4));
  int*   startA = (int*)  (ws + alloc((size_t)N * 4));
  int*   cursor = (int*)  (ws + alloc((size_t)N * 4));
  int*   col    = (int*)  (ws + alloc((size_t)E * 4));          // 6.4 MB
  int*   counter= (int*)  (ws + alloc(256));

  (void)hipMemsetAsync(deg, 0, (size_t)N * 4, stream);
  (void)hipMemsetAsync(counter, 0, 4, stream);

  k_deg<<<2048, 256, 0, stream>>>(dst, E, deg);
  k_dis<<<(N + 255) / 256, 256, 0, stream>>>(deg, dis, N);
  k_scan<<<(N + 255) / 256, 256, 0, stream>>>(deg, startA, cursor, counter, N);
  k_fill<<<2048, 256, 0, stream>>>(src, dst, E, cursor, col);
  k_gemm1<<<(N + BM - 1) / BM, 256, 0, stream>>>(X, W1, x1, N);
  k_agg_h_gemm2<<<(N + 3) / 4, 256, 0, stream>>>(x1, startA, deg, col, dis, b1, W2, x2, N);
  k_g2<<<(N + 255) / 256, 256, 0, stream>>>(x2, startA, deg, col, dis, b2, out, N);
}